// Round 10
// baseline (87.023 us; speedup 1.0000x reference)
//
#include <hip/hip_runtime.h>
#include <hip/hip_bf16.h>

#define NR  8192      // rows per view
#define M   16384     // 2*NR concatenated
#define TB  32768     // 256 rows * 128 B (one fp8 256-row tile)

constexpr float INV_T   = 2.5f;                  // 1/0.4
constexpr float SCALE_S = 1.89914134f;           // sqrt(2.5*log2(e)); s^2=2.5*log2e
constexpr float E_REFL  = 12.182493960703473f;   // exp(2.5)
constexpr unsigned UNIT_E8M0 = 0x7F7F7F7Fu;      // e8m0 scale = 2^0 in all bytes

typedef int   i32x4 __attribute__((ext_vector_type(4)));
typedef int   i32x8 __attribute__((ext_vector_type(8)));
typedef float f32x4 __attribute__((ext_vector_type(4)));

typedef const __attribute__((address_space(1))) unsigned int* gas_u32;
typedef __attribute__((address_space(3))) unsigned int*       las_u32;

__device__ __forceinline__ float fexp2(float x) {
#if __has_builtin(__builtin_amdgcn_exp2f)
    return __builtin_amdgcn_exp2f(x);
#else
    return exp2f(x);
#endif
}

// ---------------------------------------------------------------------------
// Kernel 1: L2-normalize rows; store fp8(e4m3) Z = [z1n; z2n] PRE-SCALED by
// SCALE_S (so the MX-MFMA output is directly the exp2 argument); fp32 cross
// dot; zero the rowsum array R.
// ---------------------------------------------------------------------------
__global__ __launch_bounds__(256) void norm_kernel(
    const float* __restrict__ outp, const float* __restrict__ augp,
    unsigned char* __restrict__ Zf8, float* __restrict__ R,
    float* __restrict__ posdot)
{
    int gt = blockIdx.x * 256 + threadIdx.x;
    if (gt < M) R[gt] = 0.0f;

    const int w    = threadIdx.x >> 6;
    const int lane = threadIdx.x & 63;
    const int row  = blockIdx.x * 4 + w;

    float2 a = *(const float2*)(outp + row * 128 + lane * 2);
    float2 b = *(const float2*)(augp + row * 128 + lane * 2);

    float ssa = a.x * a.x + a.y * a.y;
    float ssb = b.x * b.x + b.y * b.y;
    #pragma unroll
    for (int m = 1; m < 64; m <<= 1) {
        ssa += __shfl_xor(ssa, m);
        ssb += __shfl_xor(ssb, m);
    }
    float inva = 1.0f / fmaxf(sqrtf(ssa), 1e-12f);
    float invb = 1.0f / fmaxf(sqrtf(ssb), 1e-12f);

    float xa0 = a.x * inva, xa1 = a.y * inva;   // unit-normalized (fp32)
    float xb0 = b.x * invb, xb1 = b.y * invb;

    unsigned int pa = __builtin_amdgcn_cvt_pk_fp8_f32(xa0 * SCALE_S, xa1 * SCALE_S, 0, false);
    unsigned int pb = __builtin_amdgcn_cvt_pk_fp8_f32(xb0 * SCALE_S, xb1 * SCALE_S, 0, false);
    *(unsigned short*)(Zf8 + (size_t)row * 128 + lane * 2)        = (unsigned short)pa;
    *(unsigned short*)(Zf8 + (size_t)(NR + row) * 128 + lane * 2) = (unsigned short)pb;

    float d = xa0 * xb0 + xa1 * xb1;   // positive-pair dot stays fp32-exact
    #pragma unroll
    for (int m = 1; m < 64; m <<= 1) d += __shfl_xor(d, m);
    if (lane == 0) posdot[row] = d;
}

// ---------------------------------------------------------------------------
// Kernel 2: SYMMETRIC row sums of E = exp2(Zs Zs^T) via MX-fp8 K=128 MFMA.
// E is symmetric -> walk only the upper triangle of 64x64 tiles of 256x256:
// 2080 equal-cost blocks (~8/CU of work, 4 resident -> de-phased pipes +
// smooth tail).  Per block (a <= b): X = rows of a, Y = rows of b.
//   - Y tile (32 KB fp8) staged ONCE via swizzled global_load_lds; 1 barrier.
//   - afrag[4] (full K=128, 32B/lane) direct from L2 (Zf8 is 2 MB, L2-hot).
//   - per ct (16 cols): 2 swizzled 16B LDS reads -> b8; 4 MFMA (rt); exp2;
//     row sums accumulate in regs; col sums (= transposed-tile row sums,
//     covering the mirrored tile) horizontal-reduce + atomicAdd (a != b).
//   - diagonal blocks (a == b) contribute row sums only (full square).
// Work halves vs R9 on ALL pipes: MFMA 14.7->7.5 us, exp2 13.6->6.9 us,
// LDS 13->6.5 us per CU.
// ---------------------------------------------------------------------------
__global__ __launch_bounds__(256, 4) void gram_kernel(
    const unsigned char* __restrict__ Zf8, float* __restrict__ R)
{
    __shared__ char Ys[TB];   // 32 KB

    const int tid  = threadIdx.x;
    const int w    = tid >> 6;       // 0..3
    const int lane = tid & 63;
    const int l16  = lane & 15;
    const int lg   = lane >> 4;      // 0..3 (32-byte k-chunk / row-group)

    // decode blockIdx.x -> upper-triangular pair (a,b), a<=b.
    // S(a) = tiles before row a = 64a - a(a-1)/2
    const int bid = blockIdx.x;
    int a = (int)((129.0f - sqrtf(16641.0f - 8.0f * (float)bid)) * 0.5f);
    a = max(0, min(63, a));
    while (64 * a - (a * (a - 1)) / 2 > bid) --a;
    while (64 * (a + 1) - ((a + 1) * a) / 2 <= bid) ++a;
    const int b = a + (bid - (64 * a - (a * (a - 1)) / 2));

    const char* Zb = (const char*)Zf8;
    const char* Xg = Zb + (size_t)a * TB;
    const char* Yg = Zb + (size_t)b * TB;

    // A fragments: 64 rows per wave, full K=128 (32 B/lane), direct from L2
    i32x8 afrag[4];
    #pragma unroll
    for (int rt = 0; rt < 4; ++rt)
        afrag[rt] = *(const i32x8*)(Xg + (w * 64 + rt * 16 + l16) * 128 + lg * 32);

    // stage Y tile: LDS[linear] = G[swz(linear)], swz = XOR bits4..6 by row&7
    #pragma unroll
    for (int it = 0; it < 8; ++it) {
        int off = w * 8192 + it * 1024 + lane * 16;
        int swz = off ^ (((off >> 7) & 7) << 4);
        __builtin_amdgcn_global_load_lds((gas_u32)(Yg + swz),
                                         (las_u32)(Ys + w * 8192 + it * 1024),
                                         16, 0, 0);
    }
    __syncthreads();

    f32x4 rs[4];
    #pragma unroll
    for (int rt = 0; rt < 4; ++rt) rs[rt] = (f32x4){0.f, 0.f, 0.f, 0.f};
    const f32x4 zero4 = (f32x4){0.f, 0.f, 0.f, 0.f};
    const bool docol = (a != b);

    #pragma unroll 4
    for (int ct = 0; ct < 16; ++ct) {
        int row  = ct * 16 + l16;
        int base = row * 128 + lg * 32;
        int key  = (row & 7) << 4;
        i32x4 lo = *(const i32x4*)(Ys + (base ^ key));
        i32x4 hi = *(const i32x4*)(Ys + ((base + 16) ^ key));
        i32x8 b8 = {lo[0], lo[1], lo[2], lo[3], hi[0], hi[1], hi[2], hi[3]};

        float cp = 0.0f;
        #pragma unroll
        for (int rt = 0; rt < 4; ++rt) {
            f32x4 d = __builtin_amdgcn_mfma_scale_f32_16x16x128_f8f6f4(
                afrag[rt], b8, zero4,
                0 /*fmtA=fp8*/, 0 /*fmtB=fp8*/,
                0, UNIT_E8M0, 0, UNIT_E8M0);
            f32x4 e;
            e[0] = fexp2(d[0]); e[1] = fexp2(d[1]);
            e[2] = fexp2(d[2]); e[3] = fexp2(d[3]);
            rs[rt] += e;
            cp += (e[0] + e[1]) + (e[2] + e[3]);
        }

        if (docol) {
            // col sums of this 64-row slab -> rows of tile b (mirrored tile)
            cp += __shfl_xor(cp, 16);
            cp += __shfl_xor(cp, 32);
            if (lg == 0)
                atomicAdd(&R[b * 256 + ct * 16 + l16], cp);
        }
    }

    // row sums: reduce across the 16 lanes holding one row's columns
    #pragma unroll
    for (int rt = 0; rt < 4; ++rt)
        #pragma unroll
        for (int q = 0; q < 4; ++q) {
            float v = rs[rt][q];
            v += __shfl_xor(v, 1);  v += __shfl_xor(v, 2);
            v += __shfl_xor(v, 4);  v += __shfl_xor(v, 8);
            if (l16 == 0)
                atomicAdd(&R[a * 256 + w * 64 + rt * 16 + lg * 4 + q], v);
        }
}

// ---------------------------------------------------------------------------
// Kernel 3: loss = mean_i [ -dot_i/tau + 0.5(log(R_i - E) + log(R_{NR+i} - E)) ]
// ---------------------------------------------------------------------------
__global__ __launch_bounds__(256) void final_kernel(
    const float* __restrict__ R, const float* __restrict__ posdot,
    float* __restrict__ outv)
{
    float local = 0.0f;
    for (int i = threadIdx.x; i < NR; i += 256) {
        float d1 = R[i]      - E_REFL;
        float d2 = R[NR + i] - E_REFL;
        local += -posdot[i] * INV_T + 0.5f * (logf(d1) + logf(d2));
    }
    __shared__ float red[256];
    red[threadIdx.x] = local;
    __syncthreads();
    for (int s = 128; s > 0; s >>= 1) {
        if ((int)threadIdx.x < s) red[threadIdx.x] += red[threadIdx.x + s];
        __syncthreads();
    }
    if (threadIdx.x == 0) outv[0] = red[0] * (1.0f / NR);
}

// ---------------------------------------------------------------------------
extern "C" void kernel_launch(void* const* d_in, const int* in_sizes, int n_in,
                              void* d_out, int out_size, void* d_ws, size_t ws_size,
                              hipStream_t stream) {
    const float* outp = (const float*)d_in[0];
    const float* augp = (const float*)d_in[1];

    char* ws = (char*)d_ws;
    unsigned char* Zf8 = (unsigned char*)ws;                  // 2 MB fp8 [16384][128]
    float* R      = (float*)(ws + 2097152);                   // 16384 f32 row sums
    float* posdot = (float*)(ws + 2097152 + 65536);           // 8192 f32
    float* outf   = (float*)d_out;

    hipLaunchKernelGGL(norm_kernel, dim3(2048), dim3(256), 0, stream,
                       outp, augp, Zf8, R, posdot);

    hipLaunchKernelGGL(gram_kernel, dim3(2080), dim3(256), 0, stream,
                       Zf8, R);

    hipLaunchKernelGGL(final_kernel, dim3(1), dim3(256), 0, stream,
                       R, posdot, outf);
}